// Round 1
// baseline (818.196 us; speedup 1.0000x reference)
//
#include <hip/hip_runtime.h>
#include <stdint.h>

#define SEQ   2048
#define HID   4096
#define NH    32
#define NKV   8
#define HD    128
#define KVDIM 1024   // NKV*HD
#define KVCAT 2048   // KVDIM*2

typedef int v4i __attribute__((ext_vector_type(4)));

__device__ __forceinline__ float slot_scale(const unsigned* slots, int slot) {
    return fmaxf(__uint_as_float(slots[slot]) / 127.0f, 1e-8f);
}

__device__ __forceinline__ int q8v(float x, float s) {
    int v = (int)rintf(x / s);
    return v < -127 ? -127 : (v > 127 ? 127 : v);
}

// ---------------- absmax over 2D region (vectorized float4) ----------------
// element addr = (vid>>rshift)*ld + ((vid&cmaskv)<<2) ; contiguous: rshift=40, cmaskv=all-ones
__global__ void k_absmax(const float* __restrict__ x, long nvec, int rshift, long cmaskv,
                         long ld, unsigned* slots, int slot) {
    float m = 0.f;
    for (long vid = blockIdx.x * (long)blockDim.x + threadIdx.x; vid < nvec;
         vid += (long)gridDim.x * blockDim.x) {
        long r = vid >> rshift;
        long c = (vid & cmaskv) << 2;
        float4 v = *(const float4*)(x + r * ld + c);
        m = fmaxf(m, fmaxf(fmaxf(fabsf(v.x), fabsf(v.y)), fmaxf(fabsf(v.z), fabsf(v.w))));
    }
    for (int off = 32; off; off >>= 1) m = fmaxf(m, __shfl_xor(m, off, 64));
    __shared__ float sm[4];
    if ((threadIdx.x & 63) == 0) sm[threadIdx.x >> 6] = m;
    __syncthreads();
    if (threadIdx.x == 0) {
        float mm = fmaxf(fmaxf(sm[0], sm[1]), fmaxf(sm[2], sm[3]));
        atomicMax(slots + slot, __float_as_uint(mm));
    }
}

// ---------------- quantize f32 -> int8 (dst contiguous, src strided) ----------------
__global__ void k_quant(const float* __restrict__ x, int8_t* __restrict__ q, long nvec,
                        int rshift, long cmaskv, long ld,
                        const unsigned* __restrict__ slots, int slot) {
    float s = slot_scale(slots, slot);
    for (long vid = blockIdx.x * (long)blockDim.x + threadIdx.x; vid < nvec;
         vid += (long)gridDim.x * blockDim.x) {
        long r = vid >> rshift;
        long c = (vid & cmaskv) << 2;
        float4 v = *(const float4*)(x + r * ld + c);
        unsigned pa = (unsigned)(uint8_t)(int8_t)q8v(v.x, s)
                    | ((unsigned)(uint8_t)(int8_t)q8v(v.y, s) << 8)
                    | ((unsigned)(uint8_t)(int8_t)q8v(v.z, s) << 16)
                    | ((unsigned)(uint8_t)(int8_t)q8v(v.w, s) << 24);
        *(unsigned*)(q + vid * 4) = pa;
    }
}

// ---------------- rope cos/sin table ----------------
__global__ void k_ropetab(const int* __restrict__ pos, float* __restrict__ ct,
                          float* __restrict__ st) {
    int tid = blockIdx.x * blockDim.x + threadIdx.x;
    if (tid >= SEQ * 64) return;
    int i = tid & 63, s = tid >> 6;
    // inv_freq correctly rounded (f64 pow), angle product in f32 (matches f32 reference pipeline),
    // cos/sin of that f32 angle evaluated accurately in f64.
    double inv = 1.0 / pow(10000.0, (double)((float)(2 * i) * (1.0f / 128.0f)));
    float invf = (float)inv;
    float angf = (float)pos[s] * invf;
    double a = (double)angf;
    ct[tid] = (float)cos(a);
    st[tid] = (float)sin(a);
}

// ---------------- rope in-place + absmax ----------------
__global__ void k_rope(float* __restrict__ x, long ld, int hshift,
                       const float* __restrict__ ct, const float* __restrict__ st,
                       unsigned* slots, int slot) {
    int tid = blockIdx.x * blockDim.x + threadIdx.x;
    int i = tid & 63;
    int h = (tid >> 6) & ((1 << hshift) - 1);
    int s = tid >> (6 + hshift);
    float m = 0.f;
    if (s < SEQ) {
        long base = (long)s * ld + h * 128 + i;
        float q0 = x[base], q1 = x[base + 64];
        float c = ct[s * 64 + i], sn = st[s * 64 + i];
        float o0 = q0 * c - q1 * sn;
        float o1 = q1 * c + q0 * sn;
        x[base] = o0; x[base + 64] = o1;
        m = fmaxf(fabsf(o0), fabsf(o1));
    }
    for (int off = 32; off; off >>= 1) m = fmaxf(m, __shfl_xor(m, off, 64));
    __shared__ float sm[4];
    if ((threadIdx.x & 63) == 0) sm[threadIdx.x >> 6] = m;
    __syncthreads();
    if (threadIdx.x == 0)
        atomicMax(slots + slot, __float_as_uint(fmaxf(fmaxf(sm[0], sm[1]), fmaxf(sm[2], sm[3]))));
}

// ---------------- transpose + quantize (V -> V^T int8) ----------------
__global__ void k_transq(const float* __restrict__ src, long lds_, int8_t* __restrict__ dst,
                         long ldd, const unsigned* __restrict__ slots, int slot) {
    __shared__ float t[32][33];
    float s = slot_scale(slots, slot);
    int bx = blockIdx.x, by = blockIdx.y;
    int tid = threadIdx.x;
    int c = tid & 31, r0 = tid >> 5;
    #pragma unroll
    for (int j = 0; j < 4; j++) {
        int r = r0 + j * 8;
        t[r][c] = src[(long)(by * 32 + r) * lds_ + bx * 32 + c];
    }
    __syncthreads();
    int d = tid >> 3, k4 = (tid & 7) * 4;
    unsigned pa = 0;
    #pragma unroll
    for (int j = 0; j < 4; j++) {
        int iv = q8v(t[k4 + j][d], s);
        pa |= ((unsigned)(uint8_t)(int8_t)iv) << (8 * j);
    }
    *(unsigned*)(dst + (long)(bx * 32 + d) * ldd + by * 32 + k4) = pa;
}

// ---------------- int8 GEMM: C[M][N] = sA*sB * (A[M][K] . B[N][K]^T) ----------------
__global__ __launch_bounds__(256) void k_gemm_i8(
    const int8_t* __restrict__ A, const int8_t* __restrict__ B, float* __restrict__ C,
    int M, int N, int K, const unsigned* __restrict__ slots,
    int slotA, int slotB, int slotB2, int nsplit) {
    __shared__ int8_t As[128 * 128];
    __shared__ int8_t Bs[128 * 128];
    const v4i vzero = {0, 0, 0, 0};
    int tid = threadIdx.x, lane = tid & 63, wid = tid >> 6;
    int nbx = N >> 7;
    int nwg = gridDim.x, wg = blockIdx.x;
    int cpx = nwg >> 3;                       // nwg % 8 == 0 for all our launches
    int swz = (wg & 7) * cpx + (wg >> 3);     // XCD-aware bijective swizzle
    int bm = swz / nbx, bn = swz % nbx;
    long rowA0 = (long)bm * 128, colB0 = (long)bn * 128;
    int wrow = (wid >> 1) * 64, wcol = (wid & 1) * 64;
    v4i acc[4][4];
    #pragma unroll
    for (int m = 0; m < 4; m++)
        #pragma unroll
        for (int n = 0; n < 4; n++) acc[m][n] = vzero;
    for (int kt = 0; kt < K; kt += 128) {
        #pragma unroll
        for (int i = 0; i < 4; i++) {
            int chunk = tid + i * 256;
            int row = chunk >> 3, cc = chunk & 7;
            int sw = (cc ^ (row & 7)) * 16;   // XOR swizzle (T2)
            v4i av = *(const v4i*)(A + (rowA0 + row) * K + kt + cc * 16);
            v4i bv = *(const v4i*)(B + (colB0 + row) * K + kt + cc * 16);
            *(v4i*)(As + row * 128 + sw) = av;
            *(v4i*)(Bs + row * 128 + sw) = bv;
        }
        __syncthreads();
        #pragma unroll
        for (int ks = 0; ks < 2; ks++) {
            v4i af[4], bf[4];
            #pragma unroll
            for (int m = 0; m < 4; m++) {
                int row = wrow + m * 16 + (lane & 15);
                af[m] = *(const v4i*)(As + row * 128 + (((ks * 4 + (lane >> 4)) ^ (row & 7)) * 16));
            }
            #pragma unroll
            for (int n = 0; n < 4; n++) {
                int row = wcol + n * 16 + (lane & 15);
                bf[n] = *(const v4i*)(Bs + row * 128 + (((ks * 4 + (lane >> 4)) ^ (row & 7)) * 16));
            }
            #pragma unroll
            for (int m = 0; m < 4; m++)
                #pragma unroll
                for (int n = 0; n < 4; n++)
                    acc[m][n] = __builtin_amdgcn_mfma_i32_16x16x64_i8(af[m], bf[n], acc[m][n], 0, 0, 0);
        }
        __syncthreads();
    }
    float sA = slot_scale(slots, slotA);
    float sB1 = slot_scale(slots, slotB);
    float sB2 = slot_scale(slots, slotB2);
    #pragma unroll
    for (int m = 0; m < 4; m++) {
        long row0 = rowA0 + wrow + m * 16 + ((lane >> 4) << 2);
        #pragma unroll
        for (int n = 0; n < 4; n++) {
            int col = (int)colB0 + wcol + n * 16 + (lane & 15);
            float sc = sA * ((col < nsplit) ? sB1 : sB2);
            float* cp = C + row0 * N + col;
            #pragma unroll
            for (int r = 0; r < 4; r++) cp[(long)r * N] = sc * (float)acc[m][n][r];
        }
    }
}

// ---------------- two-pass flash attention (int8), writes int32 attn + |max| ----------------
__global__ __launch_bounds__(256) void k_attn(
    const int8_t* __restrict__ Qq, const int8_t* __restrict__ Kq, const int8_t* __restrict__ Vtq,
    int* __restrict__ AO, unsigned* slots) {
    __shared__ int8_t Qs[64 * 128];
    __shared__ int8_t Ks[64 * 128];
    __shared__ int8_t Vs[128 * 64];
    __shared__ int8_t Ps[4][16 * 64];
    const v4i vzero = {0, 0, 0, 0};
    const float SCALE_P = 1.0f / 127.0f;
    const float ISD = (float)(1.0 / (double)sqrtf(128.0f));
    int tid = threadIdx.x, lane = tid & 63, w = tid >> 6;
    int h = blockIdx.x, qb = blockIdx.y, kvh = h >> 2;
    float sq = slot_scale(slots, 5), sk = slot_scale(slots, 6);
    float sqk = sq * sk * ISD;
    // stage Q block (64 rows x 128)
    #pragma unroll
    for (int i = 0; i < 2; i++) {
        int chunk = tid + i * 256;
        int row = chunk >> 3, cc = chunk & 7;
        v4i v = *(const v4i*)(Qq + (long)(qb * 64 + row) * HID + h * 128 + cc * 16);
        *(v4i*)(Qs + row * 128 + ((cc ^ (row & 7)) * 16)) = v;
    }
    __syncthreads();
    v4i aq[2];
    #pragma unroll
    for (int ks = 0; ks < 2; ks++) {
        int row = w * 16 + (lane & 15);
        aq[ks] = *(const v4i*)(Qs + row * 128 + (((ks * 4 + (lane >> 4)) ^ (row & 7)) * 16));
    }
    float mrow[4], lrow[4];
    #pragma unroll
    for (int r = 0; r < 4; r++) { mrow[r] = -INFINITY; lrow[r] = 0.f; }
    const int q0 = qb * 64 + w * 16;
    // ---- pass 1: row max + denominator ----
    for (int kt = 0; kt <= qb; kt++) {
        __syncthreads();
        #pragma unroll
        for (int i = 0; i < 2; i++) {
            int chunk = tid + i * 256;
            int row = chunk >> 3, cc = chunk & 7;
            v4i v = *(const v4i*)(Kq + (long)(kt * 64 + row) * KVDIM + kvh * 128 + cc * 16);
            *(v4i*)(Ks + row * 128 + ((cc ^ (row & 7)) * 16)) = v;
        }
        __syncthreads();
        v4i sfr[4] = {vzero, vzero, vzero, vzero};
        #pragma unroll
        for (int ks = 0; ks < 2; ks++)
            #pragma unroll
            for (int f = 0; f < 4; f++) {
                int row = f * 16 + (lane & 15);
                v4i bk = *(const v4i*)(Ks + row * 128 + (((ks * 4 + (lane >> 4)) ^ (row & 7)) * 16));
                sfr[f] = __builtin_amdgcn_mfma_i32_16x16x64_i8(aq[ks], bk, sfr[f], 0, 0, 0);
            }
        float sv_[4][4];
        #pragma unroll
        for (int f = 0; f < 4; f++) {
            int kg = kt * 64 + f * 16 + (lane & 15);
            #pragma unroll
            for (int r = 0; r < 4; r++) {
                int qg = q0 + ((lane >> 4) << 2) + r;
                float x = (float)sfr[f][r] * sqk;
                sv_[f][r] = (kg <= qg) ? x : -1e30f;
            }
        }
        #pragma unroll
        for (int r = 0; r < 4; r++) {
            float tm = fmaxf(fmaxf(sv_[0][r], sv_[1][r]), fmaxf(sv_[2][r], sv_[3][r]));
            tm = fmaxf(tm, __shfl_xor(tm, 1, 64));
            tm = fmaxf(tm, __shfl_xor(tm, 2, 64));
            tm = fmaxf(tm, __shfl_xor(tm, 4, 64));
            tm = fmaxf(tm, __shfl_xor(tm, 8, 64));
            float mn = fmaxf(mrow[r], tm);
            float es = expf(sv_[0][r] - mn) + expf(sv_[1][r] - mn)
                     + expf(sv_[2][r] - mn) + expf(sv_[3][r] - mn);
            es += __shfl_xor(es, 1, 64);
            es += __shfl_xor(es, 2, 64);
            es += __shfl_xor(es, 4, 64);
            es += __shfl_xor(es, 8, 64);
            lrow[r] = lrow[r] * expf(mrow[r] - mn) + es;
            mrow[r] = mn;
        }
    }
    // ---- pass 2: quantized probs, int8 PV ----
    v4i of[8];
    #pragma unroll
    for (int nf = 0; nf < 8; nf++) of[nf] = vzero;
    for (int kt = 0; kt <= qb; kt++) {
        __syncthreads();
        #pragma unroll
        for (int i = 0; i < 2; i++) {
            int chunk = tid + i * 256;
            int row = chunk >> 3, cc = chunk & 7;
            v4i v = *(const v4i*)(Kq + (long)(kt * 64 + row) * KVDIM + kvh * 128 + cc * 16);
            *(v4i*)(Ks + row * 128 + ((cc ^ (row & 7)) * 16)) = v;
        }
        #pragma unroll
        for (int i = 0; i < 2; i++) {
            int chunk = tid + i * 256;
            int row = chunk >> 2, cc = chunk & 3;
            v4i v = *(const v4i*)(Vtq + (long)(kvh * 128 + row) * SEQ + kt * 64 + cc * 16);
            *(v4i*)(Vs + row * 64 + ((cc ^ (row & 3)) * 16)) = v;
        }
        __syncthreads();
        v4i sfr[4] = {vzero, vzero, vzero, vzero};
        #pragma unroll
        for (int ks = 0; ks < 2; ks++)
            #pragma unroll
            for (int f = 0; f < 4; f++) {
                int row = f * 16 + (lane & 15);
                v4i bk = *(const v4i*)(Ks + row * 128 + (((ks * 4 + (lane >> 4)) ^ (row & 7)) * 16));
                sfr[f] = __builtin_amdgcn_mfma_i32_16x16x64_i8(aq[ks], bk, sfr[f], 0, 0, 0);
            }
        #pragma unroll
        for (int f = 0; f < 4; f++) {
            int kg = kt * 64 + f * 16 + (lane & 15);
            #pragma unroll
            for (int r = 0; r < 4; r++) {
                int qg = q0 + ((lane >> 4) << 2) + r;
                float x = (float)sfr[f][r] * sqk;
                float pe = (kg <= qg) ? expf(x - mrow[r]) : 0.f;
                float p = pe / lrow[r];
                int pq = (int)rintf(p / SCALE_P);
                pq = pq > 127 ? 127 : pq;
                Ps[w][(((lane >> 4) << 2) + r) * 64 + f * 16 + (lane & 15)] = (int8_t)pq;
            }
        }
        // wave-private strip: compiler inserts lgkmcnt wait for the aliasing read below
        v4i ap = *(const v4i*)(&Ps[w][(lane & 15) * 64 + ((lane >> 4) << 4)]);
        #pragma unroll
        for (int nf = 0; nf < 8; nf++) {
            int row = nf * 16 + (lane & 15);
            v4i bv = *(const v4i*)(Vs + row * 64 + ((((lane >> 4)) ^ (row & 3)) * 16));
            of[nf] = __builtin_amdgcn_mfma_i32_16x16x64_i8(ap, bv, of[nf], 0, 0, 0);
        }
    }
    int mymax = 0;
    #pragma unroll
    for (int nf = 0; nf < 8; nf++)
        #pragma unroll
        for (int r = 0; r < 4; r++) {
            int val = of[nf][r];
            int av = val < 0 ? -val : val;
            mymax = av > mymax ? av : mymax;
            int qg = q0 + ((lane >> 4) << 2) + r;
            AO[(long)qg * HID + h * 128 + nf * 16 + (lane & 15)] = val;
        }
    #pragma unroll
    for (int off = 1; off < 64; off <<= 1) {
        int o2 = __shfl_xor(mymax, off, 64);
        mymax = o2 > mymax ? o2 : mymax;
    }
    if (lane == 0) atomicMax(slots + 8, (unsigned)mymax);
}

// ---------------- quantize attn_out (int32 -> int8), publish absmax to slot 9 ----------------
__global__ void k_quant_ao(const int* __restrict__ a, int8_t* __restrict__ q, unsigned* slots) {
    float sv = slot_scale(slots, 7);
    float spv = (1.0f / 127.0f) * sv;
    float amax = spv * (float)(int)slots[8];
    float s = fmaxf(amax / 127.0f, 1e-8f);
    long nvec = (long)SEQ * HID / 4;
    for (long vid = blockIdx.x * (long)blockDim.x + threadIdx.x; vid < nvec;
         vid += (long)gridDim.x * blockDim.x) {
        int4 v = *(const int4*)(a + vid * 4);
        int a0 = q8v(spv * (float)v.x, s);
        int a1 = q8v(spv * (float)v.y, s);
        int a2 = q8v(spv * (float)v.z, s);
        int a3 = q8v(spv * (float)v.w, s);
        unsigned pa = (unsigned)(uint8_t)(int8_t)a0
                    | ((unsigned)(uint8_t)(int8_t)a1 << 8)
                    | ((unsigned)(uint8_t)(int8_t)a2 << 16)
                    | ((unsigned)(uint8_t)(int8_t)a3 << 24);
        *(unsigned*)(q + vid * 4) = pa;
    }
    if (blockIdx.x == 0 && threadIdx.x == 0) slots[9] = __float_as_uint(amax);
}

extern "C" void kernel_launch(void* const* d_in, const int* in_sizes, int n_in,
                              void* d_out, int out_size, void* d_ws, size_t ws_size,
                              hipStream_t stream) {
    (void)in_sizes; (void)n_in; (void)out_size;
    const float* hid = (const float*)d_in[0];
    const int* pos = (const int*)d_in[2];
    const float* wqp = (const float*)d_in[3];
    const float* wkp = (const float*)d_in[4];
    const float* wvp = (const float*)d_in[5];
    const float* wop = (const float*)d_in[6];
    float* out = (float*)d_out;
    char* ws = (char*)d_ws;

    size_t o = 0;
    auto alloc = [&](size_t sz) { size_t r = o; o += (sz + 255) & ~(size_t)255; return r; };
    unsigned* slots = (unsigned*)(ws + alloc(256));
    int8_t* Xq   = (int8_t*)(ws + alloc((size_t)SEQ * HID));      // later reused as AOq
    int8_t* Wqq  = (int8_t*)(ws + alloc((size_t)HID * HID));      // later reused as Woq
    int8_t* Wkvq = (int8_t*)(ws + alloc((size_t)KVCAT * HID));
    float*  Qf   = (float*)(ws + alloc((size_t)SEQ * HID * 4));   // later reused as AOint
    float*  KVf  = (float*)(ws + alloc((size_t)SEQ * KVCAT * 4));
    int8_t* Qq   = (int8_t*)(ws + alloc((size_t)SEQ * HID));
    int8_t* Kq   = (int8_t*)(ws + alloc((size_t)SEQ * KVDIM));
    int8_t* Vtq  = (int8_t*)(ws + alloc((size_t)KVDIM * SEQ));
    float*  ctab = (float*)(ws + alloc((size_t)SEQ * 64 * 4));
    float*  stab = (float*)(ws + alloc((size_t)SEQ * 64 * 4));
    if (ws_size < o) return;  // workspace too small: fail loudly (garbage output)
    int8_t* Woq = Wqq;        // aliases (stream-ordered: safe)
    int*    AOint = (int*)Qf;
    int8_t* AOq = Xq;

    hipMemsetAsync(slots, 0, 256, stream);
    k_ropetab<<<SEQ * 64 / 256, 256, 0, stream>>>(pos, ctab, stab);
    const long CALL = 0x3FFFFFFFL;
    k_absmax<<<2048, 256, 0, stream>>>(hid, (long)SEQ * HID / 4, 40, CALL, 0, slots, 0);
    k_absmax<<<2048, 256, 0, stream>>>(wqp, (long)HID * HID / 4, 40, CALL, 0, slots, 1);
    k_absmax<<<1024, 256, 0, stream>>>(wkp, (long)KVDIM * HID / 4, 40, CALL, 0, slots, 2);
    k_absmax<<<1024, 256, 0, stream>>>(wvp, (long)KVDIM * HID / 4, 40, CALL, 0, slots, 3);
    k_absmax<<<2048, 256, 0, stream>>>(wop, (long)HID * HID / 4, 40, CALL, 0, slots, 4);
    k_quant<<<2048, 256, 0, stream>>>(hid, Xq, (long)SEQ * HID / 4, 40, CALL, 0, slots, 0);
    k_quant<<<2048, 256, 0, stream>>>(wqp, Wqq, (long)HID * HID / 4, 40, CALL, 0, slots, 1);
    k_quant<<<1024, 256, 0, stream>>>(wkp, Wkvq, (long)KVDIM * HID / 4, 40, CALL, 0, slots, 2);
    k_quant<<<1024, 256, 0, stream>>>(wvp, Wkvq + (size_t)KVDIM * HID,
                                      (long)KVDIM * HID / 4, 40, CALL, 0, slots, 3);
    k_gemm_i8<<<512, 256, 0, stream>>>(Xq, Wqq, Qf, SEQ, HID, HID, slots, 0, 1, 1, 1 << 30);
    k_gemm_i8<<<256, 256, 0, stream>>>(Xq, Wkvq, KVf, SEQ, KVCAT, HID, slots, 0, 2, 3, KVDIM);
    k_quant<<<2048, 256, 0, stream>>>(wop, Woq, (long)HID * HID / 4, 40, CALL, 0, slots, 4);
    k_rope<<<SEQ * NH * 64 / 256, 256, 0, stream>>>(Qf, HID, 5, ctab, stab, slots, 5);
    k_rope<<<SEQ * NKV * 64 / 256, 256, 0, stream>>>(KVf, KVCAT, 3, ctab, stab, slots, 6);
    k_absmax<<<1024, 256, 0, stream>>>(KVf + KVDIM, (long)SEQ * KVDIM / 4, 8, 255, KVCAT, slots, 7);
    k_quant<<<2048, 256, 0, stream>>>(Qf, Qq, (long)SEQ * HID / 4, 40, CALL, 0, slots, 5);
    k_quant<<<1024, 256, 0, stream>>>(KVf, Kq, (long)SEQ * KVDIM / 4, 8, 255, KVCAT, slots, 6);
    k_transq<<<dim3(32, 64), 256, 0, stream>>>(KVf + KVDIM, KVCAT, Vtq, SEQ, slots, 7);
    k_attn<<<dim3(NH, SEQ / 64), 256, 0, stream>>>(Qq, Kq, Vtq, AOint, slots);
    k_quant_ao<<<2048, 256, 0, stream>>>(AOint, AOq, slots);
    k_gemm_i8<<<512, 256, 0, stream>>>(AOq, Woq, out, SEQ, HID, HID, slots, 9, 4, 4, 1 << 30);
}